// Round 14
// baseline (199.378 us; speedup 1.0000x reference)
//
#include <hip/hip_runtime.h>
#include <hip/hip_bf16.h>

#define N_NODES 50000
#define N_EDGES 800000
#define DIM_IN 64
#define DIM_H 32
#define HEADS 4
#define NCLS 10
#define NEG 0.2f
#define NBUCK 196  // ceil(50000/256) buckets of 256 dst nodes
#define NPW 10     // nodes per wave in proj kernels (50000 = 5000 waves * 10)
#define FSCALE 16.0f  // fs/fd stored 16x (leaky is pos-homogeneous; attn/16)
#define LOG2E 1.44269504088896f
#define NGRP 256   // gpart groups

typedef float floatx2 __attribute__((ext_vector_type(2)));

__device__ __forceinline__ float fast_exp2(float x) {
#if __has_builtin(__builtin_amdgcn_exp2f)
    return __builtin_amdgcn_exp2f(x);
#else
    return __expf(x * 0.69314718055994531f);
#endif
}

// ---------------- CSR build (binned, single-writer adj regions) ----------------

__global__ void k_bhist(const int* __restrict__ dst, int* __restrict__ bh) {
    __shared__ int lh[NBUCK];
    for (int i = threadIdx.x; i < NBUCK; i += 256) lh[i] = 0;
    __syncthreads();
    int base = blockIdx.x * 1024 + threadIdx.x;
#pragma unroll
    for (int r = 0; r < 4; r++) {
        int e = base + r * 256;
        if (e < N_EDGES) atomicAdd(&lh[dst[e] >> 8], 1);
    }
    __syncthreads();
    for (int i = threadIdx.x; i < NBUCK; i += 256) {
        int c = lh[i];
        if (c) atomicAdd(&bh[i], c);
    }
}

__global__ void k_bscan(const int* __restrict__ bh, int* __restrict__ bbase,
                        int* __restrict__ gcur) {
    __shared__ int s[256];
    int t = threadIdx.x;
    int v = (t < NBUCK) ? bh[t] : 0;
    s[t] = v;
    __syncthreads();
    for (int off = 1; off < 256; off <<= 1) {
        int u = (t >= off) ? s[t - off] : 0;
        __syncthreads();
        s[t] += u;
        __syncthreads();
    }
    int excl = s[t] - v;
    if (t < NBUCK) {
        bbase[t] = excl;
        gcur[t] = excl;
    }
    if (t == 0) bbase[NBUCK] = N_EDGES;
}

__global__ void k_bin(const int* __restrict__ src, const int* __restrict__ dst,
                      int* __restrict__ gcur, unsigned* __restrict__ stage) {
    __shared__ int lh[NBUCK], chunk[NBUCK];
    int t = threadIdx.x;
    for (int i = t; i < NBUCK; i += 256) lh[i] = 0;
    __syncthreads();
    int e0 = blockIdx.x * 4096;
    unsigned pk[16];
    int bk[16];
#pragma unroll
    for (int r = 0; r < 16; r++) {
        int e = e0 + r * 256 + t;
        bool ok = e < N_EDGES;
        int s = ok ? src[e] : 0;
        int d = ok ? dst[e] : 0;
        bk[r] = ok ? (d >> 8) : -1;
        pk[r] = (unsigned)s | ((unsigned)(d & 255) << 16);
        if (ok) atomicAdd(&lh[bk[r]], 1);
    }
    __syncthreads();
    for (int i = t; i < NBUCK; i += 256) {
        int c = lh[i];
        chunk[i] = c ? atomicAdd(&gcur[i], c) : 0;
        lh[i] = 0;  // reuse as local cursor
    }
    __syncthreads();
#pragma unroll
    for (int r = 0; r < 16; r++) {
        if (bk[r] >= 0) {
            int lp = atomicAdd(&lh[bk[r]], 1);
            stage[chunk[bk[r]] + lp] = pk[r];
        }
    }
}

__global__ void k_csr(const unsigned* __restrict__ stage, const int* __restrict__ bbase,
                      int* __restrict__ row, unsigned short* __restrict__ adj) {
    __shared__ int lcnt[256], lcur[256], sc[256];
    int b = blockIdx.x, t = threadIdx.x;
    int s0 = bbase[b], s1 = bbase[b + 1];
    lcnt[t] = 0;
    __syncthreads();
    for (int i = s0 + t; i < s1; i += 256) atomicAdd(&lcnt[stage[i] >> 16], 1);
    __syncthreads();
    int v = lcnt[t];
    sc[t] = v;
    __syncthreads();
    for (int off = 1; off < 256; off <<= 1) {
        int u = (t >= off) ? sc[t - off] : 0;
        __syncthreads();
        sc[t] += u;
        __syncthreads();
    }
    int excl = sc[t] - v;
    int n = b * 256 + t;
    if (n < N_NODES) row[n] = s0 + excl;
    if (b == NBUCK - 1 && t == 0) row[N_NODES] = N_EDGES;
    lcur[t] = s0 + excl;
    __syncthreads();
    for (int i = s0 + t; i < s1; i += 256) {
        unsigned p = stage[i];
        int pos = atomicAdd(&lcur[p >> 16], 1);
        adj[pos] = (unsigned short)(p & 0xFFFFu);  // src fits 16 bits
    }
}

// ---------------- helpers ----------------

__device__ __forceinline__ unsigned short f2bf(float v) {  // RTN f32->bf16
    unsigned u = __builtin_bit_cast(unsigned, v);
    u += 0x7FFFu + ((u >> 16) & 1u);
    return (unsigned short)(u >> 16);
}
__device__ __forceinline__ float bfLO(unsigned u) {
    return __builtin_bit_cast(float, u << 16);
}
__device__ __forceinline__ float bfHI(unsigned u) {
    return __builtin_bit_cast(float, u & 0xFFFF0000u);
}

// ---------------- layer-1: fused embed + projection ----------------
// Per node (low-rank, 10240 MACs): x = gf_row@W_in+b_in (64->32), then
// fs|fd = x@[W1s|W1d]+[b1s|b1d] (32->256) via v_pk_fma_f32; 16x-scaled;
// fs fp8, fd bf16.
__global__ __launch_bounds__(256, 2) void k_fused1(
    const float* __restrict__ gf, const float* __restrict__ W_in,
    const float* __restrict__ b_in, const float* __restrict__ W1s,
    const float* __restrict__ b1s, const float* __restrict__ W1d,
    const float* __restrict__ b1d, unsigned char* __restrict__ fsh,
    unsigned short* __restrict__ fdh) {
    __shared__ float4 xb[4][2][8];  // [wave][dbuf][32 floats]
    int lane = threadIdx.x & 63;
    int wvl = threadIdx.x >> 6;
    int wave = (blockIdx.x * 256 + threadIdx.x) >> 6;
    int c = lane & 31, h = lane >> 5;
    int n0 = wave * NPW;
    if (n0 >= N_NODES) return;
    float wi[32];
#pragma unroll
    for (int k = 0; k < 32; k++) wi[k] = W_in[(h * 32 + k) * DIM_H + c];
    float bc = b_in[c];
    const float4* Wb = (lane < 32) ? (const float4*)W1s : (const float4*)W1d;
    const float4* bb = (lane < 32) ? (const float4*)b1s : (const float4*)b1d;
    floatx2 wA[32], wB[32];
#pragma unroll
    for (int k = 0; k < 32; k++) {
        float4 wf = Wb[k * 32 + c];
        wA[k] = {wf.x, wf.y};
        wB[k] = {wf.z, wf.w};
    }
    float4 bias = bb[c];
#pragma unroll 2
    for (int i = 0; i < NPW; i++) {  // 50000 % 10 == 0: all nodes valid
        int nu = __builtin_amdgcn_readfirstlane(n0 + i);
        const float4* gr = (const float4*)(gf + (size_t)nu * DIM_IN + h * 32);
        float a1 = 0.f;
#pragma unroll
        for (int k4 = 0; k4 < 8; k4++) {
            float4 xv = gr[k4];
            a1 += xv.x * wi[k4 * 4 + 0];
            a1 += xv.y * wi[k4 * 4 + 1];
            a1 += xv.z * wi[k4 * 4 + 2];
            a1 += xv.w * wi[k4 * 4 + 3];
        }
        a1 += __shfl_xor(a1, 32, 64);
        if (lane < 32) ((float*)&xb[wvl][i & 1][0])[c] = a1 + bc;
        floatx2 acc01 = {bias.x, bias.y}, acc23 = {bias.z, bias.w};
#pragma unroll
        for (int k4 = 0; k4 < 8; k4++) {
            float4 xv = xb[wvl][i & 1][k4];
#pragma unroll
            for (int j = 0; j < 4; j++) {
                float xk = (j == 0) ? xv.x : (j == 1) ? xv.y : (j == 2) ? xv.z : xv.w;
                floatx2 xx = {xk, xk};
                acc01 += xx * wA[k4 * 4 + j];
                acc23 += xx * wB[k4 * 4 + j];
            }
        }
        if (lane < 32) {
            int pk = __builtin_amdgcn_cvt_pk_fp8_f32(acc01.x * FSCALE, acc01.y * FSCALE,
                                                     0, false);
            pk = __builtin_amdgcn_cvt_pk_fp8_f32(acc23.x * FSCALE, acc23.y * FSCALE,
                                                 pk, true);
            *(int*)&fsh[(size_t)nu * 128 + c * 4] = pk;
        } else {
            ushort4 o;
            o.x = f2bf(acc01.x * FSCALE);
            o.y = f2bf(acc01.y * FSCALE);
            o.z = f2bf(acc23.x * FSCALE);
            o.w = f2bf(acc23.y * FSCALE);
            *(ushort4*)&fdh[(size_t)nu * 128 + c * 4] = o;
        }
    }
}

// ---------------- layer-2 projection (weights-in-registers, pk math) --------
__global__ __launch_bounds__(256, 2) void k_proj(
    const float* __restrict__ x, const float* __restrict__ Wsrc,
    const float* __restrict__ bsrc, const float* __restrict__ Wdst,
    const float* __restrict__ bdst, unsigned char* __restrict__ fsh,
    unsigned short* __restrict__ fdh) {
    int lane = threadIdx.x & 63;
    int wave = (blockIdx.x * 256 + threadIdx.x) >> 6;
    int cl = lane & 31;
    int n0 = wave * NPW;
    if (n0 >= N_NODES) return;
    const float4* Wb = (lane < 32) ? (const float4*)Wsrc : (const float4*)Wdst;
    const float4* bb = (lane < 32) ? (const float4*)bsrc : (const float4*)bdst;
    floatx2 wA[32], wB[32];
#pragma unroll
    for (int k = 0; k < 32; k++) {
        float4 wf = Wb[k * 32 + cl];
        wA[k] = {wf.x, wf.y};
        wB[k] = {wf.z, wf.w};
    }
    float4 bias = bb[cl];
#pragma unroll 2
    for (int i = 0; i < NPW; i++) {
        int nu = __builtin_amdgcn_readfirstlane(n0 + i);
        const float4* xr = (const float4*)(x + (size_t)nu * DIM_H);
        floatx2 acc01 = {bias.x, bias.y}, acc23 = {bias.z, bias.w};
#pragma unroll
        for (int k4 = 0; k4 < 8; k4++) {
            float4 xv = xr[k4];
#pragma unroll
            for (int j = 0; j < 4; j++) {
                float xk = (j == 0) ? xv.x : (j == 1) ? xv.y : (j == 2) ? xv.z : xv.w;
                floatx2 xx = {xk, xk};
                acc01 += xx * wA[k4 * 4 + j];
                acc23 += xx * wB[k4 * 4 + j];
            }
        }
        if (lane < 32) {
            int pk = __builtin_amdgcn_cvt_pk_fp8_f32(acc01.x * FSCALE, acc01.y * FSCALE,
                                                     0, false);
            pk = __builtin_amdgcn_cvt_pk_fp8_f32(acc23.x * FSCALE, acc23.y * FSCALE,
                                                 pk, true);
            *(int*)&fsh[(size_t)nu * 128 + cl * 4] = pk;
        } else {
            ushort4 o;
            o.x = f2bf(acc01.x * FSCALE);
            o.y = f2bf(acc01.y * FSCALE);
            o.z = f2bf(acc23.x * FSCALE);
            o.w = f2bf(acc23.y * FSCALE);
            *(ushort4*)&fdh[(size_t)nu * 128 + cl * 4] = o;
        }
    }
}

// ---------------- GAT gather (1 wave per block, 16 lanes/edge) ---------------
// One 64-thread block per destination node -> independent wave slots, no
// intra-block coupling, no syncthreads (mode 1 uses direct global atomics
// spread over NGRP groups). Lane = (eq=lane>>4 edge slot, sub=lane&15); lane
// owns 8 dims of its edge's 128B fp8 row (uint2 load; 4 edges/instruction).
// Head h=sub>>2: score reduce = shfl_xor(1)+shfl_xor(2) (DPP quad-perm).
// attn prescaled by log2e/16; 0.25/16 folded into inv.
__device__ __forceinline__ void quad_acc(uint2 u, const floatx2* fd8,
                                         const floatx2* a8, floatx2* acc,
                                         float& den, bool valid) {
    floatx2 f0 = __builtin_amdgcn_cvt_pk_f32_fp8((int)u.x, false);
    floatx2 f1 = __builtin_amdgcn_cvt_pk_f32_fp8((int)u.x, true);
    floatx2 f2 = __builtin_amdgcn_cvt_pk_f32_fp8((int)u.y, false);
    floatx2 f3 = __builtin_amdgcn_cvt_pk_f32_fp8((int)u.y, true);
    floatx2 t0 = f0 + fd8[0];
    floatx2 t1 = f1 + fd8[1];
    floatx2 t2 = f2 + fd8[2];
    floatx2 t3 = f3 + fd8[3];
    floatx2 n0 = t0 * NEG, n1 = t1 * NEG, n2 = t2 * NEG, n3 = t3 * NEG;
    floatx2 l0, l1, l2, l3;
    l0.x = fmaxf(t0.x, n0.x); l0.y = fmaxf(t0.y, n0.y);
    l1.x = fmaxf(t1.x, n1.x); l1.y = fmaxf(t1.y, n1.y);
    l2.x = fmaxf(t2.x, n2.x); l2.y = fmaxf(t2.y, n2.y);
    l3.x = fmaxf(t3.x, n3.x); l3.y = fmaxf(t3.y, n3.y);
    floatx2 d = l0 * a8[0] + l1 * a8[1] + l2 * a8[2] + l3 * a8[3];
    float p = d.x + d.y;
    p += __shfl_xor(p, 1, 64);  // DPP quad_perm
    p += __shfl_xor(p, 2, 64);  // DPP quad_perm
    float w = fast_exp2(p);
    if (!valid) w = 0.f;
    den += w;
    floatx2 wv = {w, w};
    acc[0] += wv * f0;
    acc[1] += wv * f1;
    acc[2] += wv * f2;
    acc[3] += wv * f3;
}

__global__ __launch_bounds__(64) void k_gather(
    const unsigned char* __restrict__ fsh, const unsigned short* __restrict__ fdh,
    const float* __restrict__ attn, const int* __restrict__ row,
    const unsigned short* __restrict__ adj, float* __restrict__ xout,
    float* __restrict__ gpart, int mode) {  // mode 0: relu+store x; 1: mean reduce
    int lane = threadIdx.x;
    int n = blockIdx.x;  // one node per block
    int sub = lane & 15, eq = lane >> 4;
    unsigned suboff = (unsigned)sub << 3;  // 8B per lane within 128B row
    const float asc = LOG2E / FSCALE;
    floatx2 a8[4], fd8[4];
    {
        const float4* ap = (const float4*)attn + sub * 2;
        float4 t0 = ap[0], t1 = ap[1];
        a8[0] = {t0.x * asc, t0.y * asc};
        a8[1] = {t0.z * asc, t0.w * asc};
        a8[2] = {t1.x * asc, t1.y * asc};
        a8[3] = {t1.z * asc, t1.w * asc};
        uint4 fdu = *(const uint4*)(fdh + (size_t)n * 128 + sub * 8);
        fd8[0] = {bfLO(fdu.x), bfHI(fdu.x)};
        fd8[1] = {bfLO(fdu.y), bfHI(fdu.y)};
        fd8[2] = {bfLO(fdu.z), bfHI(fdu.z)};
        fd8[3] = {bfLO(fdu.w), bfHI(fdu.w)};
    }
    floatx2 acc[4] = {{0.f, 0.f}, {0.f, 0.f}, {0.f, 0.f}, {0.f, 0.f}};
    float den = 0.f;
    int beg = row[n], end = row[n + 1];
    for (int base = beg; base < end; base += 64) {
        int m = end - base;
        if (m > 64) m = 64;
        int myadj = (lane < m) ? (int)adj[base + lane] : 0;
        int j = 0;
        for (; j + 16 <= m; j += 16) {  // 4 quads = 16 edges, 4 loads in flight
            unsigned o0 = ((unsigned)__shfl(myadj, j + 0 + eq, 64) << 7) + suboff;
            unsigned o1 = ((unsigned)__shfl(myadj, j + 4 + eq, 64) << 7) + suboff;
            unsigned o2 = ((unsigned)__shfl(myadj, j + 8 + eq, 64) << 7) + suboff;
            unsigned o3 = ((unsigned)__shfl(myadj, j + 12 + eq, 64) << 7) + suboff;
            uint2 u0 = *(const uint2*)(fsh + o0);
            uint2 u1 = *(const uint2*)(fsh + o1);
            uint2 u2 = *(const uint2*)(fsh + o2);
            uint2 u3 = *(const uint2*)(fsh + o3);
            quad_acc(u0, fd8, a8, acc, den, true);
            quad_acc(u1, fd8, a8, acc, den, true);
            quad_acc(u2, fd8, a8, acc, den, true);
            quad_acc(u3, fd8, a8, acc, den, true);
        }
        for (; j + 8 <= m; j += 8) {  // 2 quads = 8 edges
            unsigned o0 = ((unsigned)__shfl(myadj, j + 0 + eq, 64) << 7) + suboff;
            unsigned o1 = ((unsigned)__shfl(myadj, j + 4 + eq, 64) << 7) + suboff;
            uint2 u0 = *(const uint2*)(fsh + o0);
            uint2 u1 = *(const uint2*)(fsh + o1);
            quad_acc(u0, fd8, a8, acc, den, true);
            quad_acc(u1, fd8, a8, acc, den, true);
        }
        for (; j < m; j += 4) {  // tail quads (possibly partial)
            int idx = j + eq;
            bool valid = idx < m;
            unsigned o = ((unsigned)__shfl(myadj, valid ? idx : j, 64) << 7) + suboff;
            uint2 u = *(const uint2*)(fsh + o);
            quad_acc(u, fd8, a8, acc, den, valid);
        }
    }
    // combine the 4 edge slots
    den += __shfl_xor(den, 16, 64);
    den += __shfl_xor(den, 32, 64);
    float av[8] = {acc[0].x, acc[0].y, acc[1].x, acc[1].y,
                   acc[2].x, acc[2].y, acc[3].x, acc[3].y};
#pragma unroll
    for (int j = 0; j < 8; j++) {
        av[j] += __shfl_xor(av[j], 16, 64);
        av[j] += __shfl_xor(av[j], 32, 64);
    }
    float inv = den > 0.f ? (0.25f / FSCALE) / den : 0.f;  // head-mean + unscale
    float o[8];
#pragma unroll
    for (int j = 0; j < 8; j++) {
        float v = av[j] * inv;
        v += __shfl_xor(v, 4, 64);  // head mean: sum over lane bits 2,3
        v += __shfl_xor(v, 8, 64);
        o[j] = v;
    }
    if (mode == 0) {
        if (lane < 4) {  // lane holds output dims lane*8..+7 (head-0 copy)
            float4 lo, hi;
            lo.x = fmaxf(o[0], 0.f); lo.y = fmaxf(o[1], 0.f);
            lo.z = fmaxf(o[2], 0.f); lo.w = fmaxf(o[3], 0.f);
            hi.x = fmaxf(o[4], 0.f); hi.y = fmaxf(o[5], 0.f);
            hi.z = fmaxf(o[6], 0.f); hi.w = fmaxf(o[7], 0.f);
            float4* xp = (float4*)(xout + (size_t)n * 32 + lane * 8);
            xp[0] = lo;
            xp[1] = hi;
        }
    } else {
        if (lane < 4) {
            float* gp = gpart + (blockIdx.x & (NGRP - 1)) * 32 + lane * 8;
#pragma unroll
            for (int j = 0; j < 8; j++) atomicAdd(&gp[j], o[j]);
        }
    }
}

__global__ void k_final(const float* __restrict__ gpart, const float* __restrict__ Wh1,
                        const float* __restrict__ bh1, const float* __restrict__ Wh2,
                        const float* __restrict__ bh2, float* __restrict__ out) {
    __shared__ float gv[32], gh[32], lg[16];
    int t = threadIdx.x;
    if (t < 32) {
        float s = 0.f;
        for (int b = 0; b < NGRP; b++) s += gpart[b * 32 + t];
        gv[t] = s * (1.f / (float)N_NODES);
    }
    __syncthreads();
    if (t < 32) {
        float s = bh1[t];
        for (int d = 0; d < 32; d++) s += gv[d] * Wh1[d * 32 + t];
        gh[t] = s > 0.f ? s : 0.f;
    }
    __syncthreads();
    if (t < NCLS) {
        float s = bh2[t];
        for (int j = 0; j < 32; j++) s += gh[j] * Wh2[j * NCLS + t];
        lg[t] = s;
    }
    __syncthreads();
    if (t == 0) {
        float m = lg[0];
        for (int c = 1; c < NCLS; c++) m = fmaxf(m, lg[c]);
        float ex[NCLS], sum = 0.f;
        for (int c = 0; c < NCLS; c++) {
            ex[c] = __expf(lg[c] - m);
            sum += ex[c];
        }
        float inv = 1.f / sum;
        for (int c = 0; c < NCLS; c++) out[c] = ex[c] * inv;
    }
}

extern "C" void kernel_launch(void* const* d_in, const int* in_sizes, int n_in,
                              void* d_out, int out_size, void* d_ws, size_t ws_size,
                              hipStream_t stream) {
    const float* g_feats = (const float*)d_in[0];
    const int* edge_src = (const int*)d_in[1];
    const int* edge_dst = (const int*)d_in[2];
    const float* W_in = (const float*)d_in[3];
    const float* b_in = (const float*)d_in[4];
    const float* W1_src = (const float*)d_in[5];
    const float* b1_src = (const float*)d_in[6];
    const float* W1_dst = (const float*)d_in[7];
    const float* b1_dst = (const float*)d_in[8];
    const float* attn1 = (const float*)d_in[9];
    const float* W2_src = (const float*)d_in[10];
    const float* b2_src = (const float*)d_in[11];
    const float* W2_dst = (const float*)d_in[12];
    const float* b2_dst = (const float*)d_in[13];
    const float* attn2 = (const float*)d_in[14];
    const float* Wh1 = (const float*)d_in[15];
    const float* bh1 = (const float*)d_in[16];
    const float* Wh2 = (const float*)d_in[17];
    const float* bh2 = (const float*)d_in[18];

    // workspace layout
    float* x = (float*)d_ws;                                          // N*32 f32
    unsigned char* fsh = (unsigned char*)(x + (size_t)N_NODES * 32);  // N*128 fp8
    unsigned short* fdh = (unsigned short*)(fsh + (size_t)N_NODES * 128);  // N*128 bf16
    float* gpart = (float*)(fdh + (size_t)N_NODES * 128);             // NGRP*32
    int* bh = (int*)(gpart + NGRP * 32);                              // NBUCK
    int* bbase = bh + NBUCK;                                          // NBUCK+1
    int* gcur = bbase + NBUCK + 1;                                    // NBUCK
    int* row = gcur + NBUCK;                                          // N+1
    unsigned* stage = (unsigned*)(row + N_NODES + 1);                 // E
    unsigned short* adj = (unsigned short*)(stage + N_EDGES);         // E u16

    const int WB = (N_NODES / NPW + 3) / 4;  // 1250 blocks: 4 waves x 10 nodes

    // zero gpart + bucket histogram in one memset (adjacent)
    hipMemsetAsync(gpart, 0, (NGRP * 32 + NBUCK) * sizeof(int), stream);

    // CSR build (binned)
    k_bhist<<<(N_EDGES + 1023) / 1024, 256, 0, stream>>>(edge_dst, bh);
    k_bscan<<<1, 256, 0, stream>>>(bh, bbase, gcur);
    k_bin<<<(N_EDGES + 4095) / 4096, 256, 0, stream>>>(edge_src, edge_dst, gcur, stage);
    k_csr<<<NBUCK, 256, 0, stream>>>(stage, bbase, row, adj);

    // layer 1 (pipeline-fused embed+proj, low-rank path)
    k_fused1<<<WB, 256, 0, stream>>>(g_feats, W_in, b_in, W1_src, b1_src, W1_dst,
                                     b1_dst, fsh, fdh);
    k_gather<<<N_NODES, 64, 0, stream>>>(fsh, fdh, attn1, row, adj, x, gpart, 0);

    // layer 2 (gather fuses the graph-mean reduction)
    k_proj<<<WB, 256, 0, stream>>>(x, W2_src, b2_src, W2_dst, b2_dst, fsh, fdh);
    k_gather<<<N_NODES, 64, 0, stream>>>(fsh, fdh, attn2, row, adj, x, gpart, 1);

    k_final<<<1, 256, 0, stream>>>(gpart, Wh1, bh1, Wh2, bh2, (float*)d_out);
}

// Round 15
// 188.412 us; speedup vs baseline: 1.0582x; 1.0582x over previous
//
#include <hip/hip_runtime.h>
#include <hip/hip_bf16.h>

#define N_NODES 50000
#define N_EDGES 800000
#define DIM_IN 64
#define DIM_H 32
#define HEADS 4
#define NCLS 10
#define NEG 0.2f
#define NBUCK 196  // ceil(50000/256) buckets of 256 dst nodes
#define NPW 25     // nodes per wave in proj kernels (50000 = 2000 waves * 25)
#define FSCALE 16.0f  // fs/fd stored 16x (leaky is pos-homogeneous; attn/16)
#define LOG2E 1.44269504088896f
#define NGRP 256   // gpart groups
#define NPG 8      // nodes per gather wave (pipelined)

typedef float floatx2 __attribute__((ext_vector_type(2)));

__device__ __forceinline__ float fast_exp2(float x) {
#if __has_builtin(__builtin_amdgcn_exp2f)
    return __builtin_amdgcn_exp2f(x);
#else
    return __expf(x * 0.69314718055994531f);
#endif
}

// ---------------- CSR build (binned, single-writer adj regions) ----------------

__global__ void k_bscan(const int* __restrict__ bh, int* __restrict__ bbase,
                        int* __restrict__ gcur) {
    __shared__ int s[256];
    int t = threadIdx.x;
    int v = (t < NBUCK) ? bh[t] : 0;
    s[t] = v;
    __syncthreads();
    for (int off = 1; off < 256; off <<= 1) {
        int u = (t >= off) ? s[t - off] : 0;
        __syncthreads();
        s[t] += u;
        __syncthreads();
    }
    int excl = s[t] - v;
    if (t < NBUCK) {
        bbase[t] = excl;
        gcur[t] = excl;
    }
    if (t == 0) bbase[NBUCK] = N_EDGES;
}

__global__ void k_bin(const int* __restrict__ src, const int* __restrict__ dst,
                      int* __restrict__ gcur, unsigned* __restrict__ stage) {
    __shared__ int lh[NBUCK], chunk[NBUCK];
    int t = threadIdx.x;
    for (int i = t; i < NBUCK; i += 256) lh[i] = 0;
    __syncthreads();
    int e0 = blockIdx.x * 4096;
    unsigned pk[16];
    int bk[16];
#pragma unroll
    for (int r = 0; r < 16; r++) {
        int e = e0 + r * 256 + t;
        bool ok = e < N_EDGES;
        int s = ok ? src[e] : 0;
        int d = ok ? dst[e] : 0;
        bk[r] = ok ? (d >> 8) : -1;
        pk[r] = (unsigned)s | ((unsigned)(d & 255) << 16);
        if (ok) atomicAdd(&lh[bk[r]], 1);
    }
    __syncthreads();
    for (int i = t; i < NBUCK; i += 256) {
        int c = lh[i];
        chunk[i] = c ? atomicAdd(&gcur[i], c) : 0;
        lh[i] = 0;  // reuse as local cursor
    }
    __syncthreads();
#pragma unroll
    for (int r = 0; r < 16; r++) {
        if (bk[r] >= 0) {
            int lp = atomicAdd(&lh[bk[r]], 1);
            stage[chunk[bk[r]] + lp] = pk[r];
        }
    }
}

__global__ void k_csr(const unsigned* __restrict__ stage, const int* __restrict__ bbase,
                      int* __restrict__ row, unsigned short* __restrict__ adj) {
    __shared__ int lcnt[256], lcur[256], sc[256];
    int b = blockIdx.x, t = threadIdx.x;
    int s0 = bbase[b], s1 = bbase[b + 1];
    lcnt[t] = 0;
    __syncthreads();
    for (int i = s0 + t; i < s1; i += 256) atomicAdd(&lcnt[stage[i] >> 16], 1);
    __syncthreads();
    int v = lcnt[t];
    sc[t] = v;
    __syncthreads();
    for (int off = 1; off < 256; off <<= 1) {
        int u = (t >= off) ? sc[t - off] : 0;
        __syncthreads();
        sc[t] += u;
        __syncthreads();
    }
    int excl = sc[t] - v;
    int n = b * 256 + t;
    if (n < N_NODES) row[n] = s0 + excl;
    if (b == NBUCK - 1 && t == 0) row[N_NODES] = N_EDGES;
    lcur[t] = s0 + excl;
    __syncthreads();
    for (int i = s0 + t; i < s1; i += 256) {
        unsigned p = stage[i];
        int pos = atomicAdd(&lcur[p >> 16], 1);
        adj[pos] = (unsigned short)(p & 0xFFFFu);  // src fits 16 bits
    }
}

// ---------------- helpers ----------------

__device__ __forceinline__ unsigned short f2bf(float v) {  // RTN f32->bf16
    unsigned u = __builtin_bit_cast(unsigned, v);
    u += 0x7FFFu + ((u >> 16) & 1u);
    return (unsigned short)(u >> 16);
}
__device__ __forceinline__ float bf2f(unsigned short h) {
    return __builtin_bit_cast(float, (unsigned)h << 16);
}

// ---------------- fused: layer-1 embed+proj  ||  bucket histogram ----------------
// Blocks [0, F1B): per node x=gf@W_in+b_in (64->32) then fs|fd=x@[W1s|W1d]+b
// (32->256) via pk_fma; 16x-scaled; fs fp8, fd bf16.
// Blocks [F1B, F1B+HB): LDS-aggregated histogram of dst buckets (independent
// work co-scheduled to hide it under the projection).
#define F1B 500  // 500 blocks * 4 waves * 25 nodes = 50000
#define HB 782   // ceil(800000/1024)
__global__ __launch_bounds__(256, 2) void k_f1h(
    const float* __restrict__ gf, const float* __restrict__ W_in,
    const float* __restrict__ b_in, const float* __restrict__ W1s,
    const float* __restrict__ b1s, const float* __restrict__ W1d,
    const float* __restrict__ b1d, unsigned char* __restrict__ fsh,
    unsigned short* __restrict__ fdh, const int* __restrict__ dst,
    int* __restrict__ bhist) {
    __shared__ float4 xb[4][2][8];  // [wave][dbuf][32 floats]
    __shared__ int lh[NBUCK];
    if (blockIdx.x >= F1B) {  // histogram part
        for (int i = threadIdx.x; i < NBUCK; i += 256) lh[i] = 0;
        __syncthreads();
        int base = (blockIdx.x - F1B) * 1024 + threadIdx.x;
#pragma unroll
        for (int r = 0; r < 4; r++) {
            int e = base + r * 256;
            if (e < N_EDGES) atomicAdd(&lh[dst[e] >> 8], 1);
        }
        __syncthreads();
        for (int i = threadIdx.x; i < NBUCK; i += 256) {
            int c = lh[i];
            if (c) atomicAdd(&bhist[i], c);
        }
        return;
    }
    int lane = threadIdx.x & 63;
    int wvl = threadIdx.x >> 6;
    int wave = (blockIdx.x * 256 + threadIdx.x) >> 6;
    int c = lane & 31, h = lane >> 5;
    int n0 = wave * NPW;
    float wi[32];
#pragma unroll
    for (int k = 0; k < 32; k++) wi[k] = W_in[(h * 32 + k) * DIM_H + c];
    float bc = b_in[c];
    const float4* Wb = (lane < 32) ? (const float4*)W1s : (const float4*)W1d;
    const float4* bb = (lane < 32) ? (const float4*)b1s : (const float4*)b1d;
    floatx2 wA[32], wB[32];
#pragma unroll
    for (int k = 0; k < 32; k++) {
        float4 wf = Wb[k * 32 + c];
        wA[k] = {wf.x, wf.y};
        wB[k] = {wf.z, wf.w};
    }
    float4 bias = bb[c];
#pragma unroll 2
    for (int i = 0; i < NPW; i++) {  // 50000 % 25 == 0: all nodes valid
        int nu = __builtin_amdgcn_readfirstlane(n0 + i);
        const float4* gr = (const float4*)(gf + (size_t)nu * DIM_IN + h * 32);
        float a1 = 0.f;
#pragma unroll
        for (int k4 = 0; k4 < 8; k4++) {
            float4 xv = gr[k4];
            a1 += xv.x * wi[k4 * 4 + 0];
            a1 += xv.y * wi[k4 * 4 + 1];
            a1 += xv.z * wi[k4 * 4 + 2];
            a1 += xv.w * wi[k4 * 4 + 3];
        }
        a1 += __shfl_xor(a1, 32, 64);
        if (lane < 32) ((float*)&xb[wvl][i & 1][0])[c] = a1 + bc;
        floatx2 acc01 = {bias.x, bias.y}, acc23 = {bias.z, bias.w};
#pragma unroll
        for (int k4 = 0; k4 < 8; k4++) {
            float4 xv = xb[wvl][i & 1][k4];
#pragma unroll
            for (int j = 0; j < 4; j++) {
                float xk = (j == 0) ? xv.x : (j == 1) ? xv.y : (j == 2) ? xv.z : xv.w;
                floatx2 xx = {xk, xk};
                acc01 += xx * wA[k4 * 4 + j];
                acc23 += xx * wB[k4 * 4 + j];
            }
        }
        if (lane < 32) {
            int pk = __builtin_amdgcn_cvt_pk_fp8_f32(acc01.x * FSCALE, acc01.y * FSCALE,
                                                     0, false);
            pk = __builtin_amdgcn_cvt_pk_fp8_f32(acc23.x * FSCALE, acc23.y * FSCALE,
                                                 pk, true);
            *(int*)&fsh[(size_t)nu * 128 + c * 4] = pk;
        } else {
            ushort4 o;
            o.x = f2bf(acc01.x * FSCALE);
            o.y = f2bf(acc01.y * FSCALE);
            o.z = f2bf(acc23.x * FSCALE);
            o.w = f2bf(acc23.y * FSCALE);
            *(ushort4*)&fdh[(size_t)nu * 128 + c * 4] = o;
        }
    }
}

// ---------------- layer-2 projection (weights-in-registers, pk math) --------
__global__ __launch_bounds__(256, 2) void k_proj(
    const float* __restrict__ x, const float* __restrict__ Wsrc,
    const float* __restrict__ bsrc, const float* __restrict__ Wdst,
    const float* __restrict__ bdst, unsigned char* __restrict__ fsh,
    unsigned short* __restrict__ fdh) {
    int lane = threadIdx.x & 63;
    int wave = (blockIdx.x * 256 + threadIdx.x) >> 6;
    int cl = lane & 31;
    int n0 = wave * NPW;
    if (n0 >= N_NODES) return;
    const float4* Wb = (lane < 32) ? (const float4*)Wsrc : (const float4*)Wdst;
    const float4* bb = (lane < 32) ? (const float4*)bsrc : (const float4*)bdst;
    floatx2 wA[32], wB[32];
#pragma unroll
    for (int k = 0; k < 32; k++) {
        float4 wf = Wb[k * 32 + cl];
        wA[k] = {wf.x, wf.y};
        wB[k] = {wf.z, wf.w};
    }
    float4 bias = bb[cl];
#pragma unroll 2
    for (int i = 0; i < NPW; i++) {
        int nu = __builtin_amdgcn_readfirstlane(n0 + i);
        const float4* xr = (const float4*)(x + (size_t)nu * DIM_H);
        floatx2 acc01 = {bias.x, bias.y}, acc23 = {bias.z, bias.w};
#pragma unroll
        for (int k4 = 0; k4 < 8; k4++) {
            float4 xv = xr[k4];
#pragma unroll
            for (int j = 0; j < 4; j++) {
                float xk = (j == 0) ? xv.x : (j == 1) ? xv.y : (j == 2) ? xv.z : xv.w;
                floatx2 xx = {xk, xk};
                acc01 += xx * wA[k4 * 4 + j];
                acc23 += xx * wB[k4 * 4 + j];
            }
        }
        if (lane < 32) {
            int pk = __builtin_amdgcn_cvt_pk_fp8_f32(acc01.x * FSCALE, acc01.y * FSCALE,
                                                     0, false);
            pk = __builtin_amdgcn_cvt_pk_fp8_f32(acc23.x * FSCALE, acc23.y * FSCALE,
                                                 pk, true);
            *(int*)&fsh[(size_t)nu * 128 + cl * 4] = pk;
        } else {
            ushort4 o;
            o.x = f2bf(acc01.x * FSCALE);
            o.y = f2bf(acc01.y * FSCALE);
            o.z = f2bf(acc23.x * FSCALE);
            o.w = f2bf(acc23.y * FSCALE);
            *(ushort4*)&fdh[(size_t)nu * 128 + cl * 4] = o;
        }
    }
}

// ---------------- GAT gather (8 nodes/wave, cross-node pipelined) ------------
// One wave per 8 consecutive nodes. Row bounds for all 8 loaded once (lane<9)
// and broadcast via shfl. Node i+1's fd row + first adjacency chunk are
// prefetched BEFORE node i's edge loop, hiding the per-node startup latency
// chain (row->fd->adj->fs) under compute. Inner loop = R12's proven 2-edge
// scheme: lane=(e2=lane>>5, sub=lane&31), 4B fp8 dword per lane, pk math,
// 3 shfl_xor score reduce, base-2 exp with prescaled attn.
__device__ __forceinline__ void pair_acc(unsigned u, floatx2 fd01, floatx2 fd23,
                                         floatx2 a01, floatx2 a23, floatx2& acc01,
                                         floatx2& acc23, float& den, bool valid) {
    floatx2 f01 = __builtin_amdgcn_cvt_pk_f32_fp8((int)u, false);
    floatx2 f23 = __builtin_amdgcn_cvt_pk_f32_fp8((int)u, true);
    floatx2 t01 = f01 + fd01;
    floatx2 t23 = f23 + fd23;
    floatx2 n01 = t01 * NEG;
    floatx2 n23 = t23 * NEG;
    floatx2 l01, l23;
    l01.x = fmaxf(t01.x, n01.x);
    l01.y = fmaxf(t01.y, n01.y);
    l23.x = fmaxf(t23.x, n23.x);
    l23.y = fmaxf(t23.y, n23.y);
    floatx2 d = l01 * a01 + l23 * a23;  // pk_mul + pk_fma
    float p = d.x + d.y;
    p += __shfl_xor(p, 1, 64);
    p += __shfl_xor(p, 2, 64);
    p += __shfl_xor(p, 4, 64);
    float w = fast_exp2(p);
    if (!valid) w = 0.f;
    den += w;
    floatx2 wv = {w, w};
    acc01 += wv * f01;
    acc23 += wv * f23;
}

__global__ __launch_bounds__(256) void k_gather(
    const unsigned char* __restrict__ fsh, const unsigned short* __restrict__ fdh,
    const float* __restrict__ attn, const int* __restrict__ row,
    const unsigned short* __restrict__ adj, float* __restrict__ xout,
    float* __restrict__ gpart, int mode) {  // mode 0: relu+store x; 1: mean reduce
    int lane = threadIdx.x & 63;
    int wg = (blockIdx.x * 256 + threadIdx.x) >> 6;
    int nb = wg * NPG;
    if (nb >= N_NODES) return;  // 50000 % 8 == 0: valid waves have all 8 nodes
    int sub = lane & 31, e2 = lane >> 5;
    unsigned suboff = (unsigned)sub << 2;  // 4B per lane within 128B row
    const float asc = LOG2E / FSCALE;
    float4 a4 = ((const float4*)attn)[sub];
    floatx2 a01 = {a4.x * asc, a4.y * asc};
    floatx2 a23 = {a4.z * asc, a4.w * asc};
    int rv = (lane < NPG + 1) ? row[nb + lane] : 0;  // bounds for 8 nodes
    // node-0 prefetch
    ushort4 fdu = *(const ushort4*)(fdh + (size_t)nb * 128 + sub * 4);
    int beg = __shfl(rv, 0, 64), end = __shfl(rv, 1, 64);
    {
        int m0 = end - beg;
        if (m0 > 64) m0 = 64;
        int a0 = (lane < m0) ? (int)adj[beg + lane] : 0;
        rv = rv;  // keep
        // stash in adjc
        // (declared below)
        // nothing
        // placeholder comment to keep structure clear
        (void)a0;
    }
    int m0i = end - beg;
    if (m0i > 64) m0i = 64;
    int adjc = (lane < m0i) ? (int)adj[beg + lane] : 0;
    float4 racc = {0.f, 0.f, 0.f, 0.f};
#pragma unroll 1
    for (int i = 0; i < NPG; i++) {
        int n = nb + i;
        // prefetch node i+1 (independent loads, hidden under this node's work)
        ushort4 fdu_n = fdu;
        int adjc_n = 0, beg_n = 0, end_n = 0;
        if (i < NPG - 1) {
            beg_n = __shfl(rv, i + 1, 64);
            end_n = __shfl(rv, i + 2, 64);
            fdu_n = *(const ushort4*)(fdh + (size_t)(n + 1) * 128 + sub * 4);
            int mn = end_n - beg_n;
            if (mn > 64) mn = 64;
            adjc_n = (lane < mn) ? (int)adj[beg_n + lane] : 0;
        }
        floatx2 fd01 = {bf2f(fdu.x), bf2f(fdu.y)};
        floatx2 fd23 = {bf2f(fdu.z), bf2f(fdu.w)};
        floatx2 acc01 = {0.f, 0.f}, acc23 = {0.f, 0.f};
        float den = 0.f;
        for (int base = beg; base < end; base += 64) {
            int m = end - base;
            if (m > 64) m = 64;
            int myadj;
            if (base == beg) {
                myadj = adjc;
            } else {
                myadj = (lane < m) ? (int)adj[base + lane] : 0;
            }
            int j = 0;
            for (; j + 16 <= m; j += 16) {  // 8 pair-slots = 16 edges
                unsigned o0 = ((unsigned)__shfl(myadj, j + 0 + e2, 64) << 7) + suboff;
                unsigned o1 = ((unsigned)__shfl(myadj, j + 2 + e2, 64) << 7) + suboff;
                unsigned o2 = ((unsigned)__shfl(myadj, j + 4 + e2, 64) << 7) + suboff;
                unsigned o3 = ((unsigned)__shfl(myadj, j + 6 + e2, 64) << 7) + suboff;
                unsigned o4 = ((unsigned)__shfl(myadj, j + 8 + e2, 64) << 7) + suboff;
                unsigned o5 = ((unsigned)__shfl(myadj, j + 10 + e2, 64) << 7) + suboff;
                unsigned o6 = ((unsigned)__shfl(myadj, j + 12 + e2, 64) << 7) + suboff;
                unsigned o7 = ((unsigned)__shfl(myadj, j + 14 + e2, 64) << 7) + suboff;
                unsigned u0 = *(const unsigned*)(fsh + o0);
                unsigned u1 = *(const unsigned*)(fsh + o1);
                unsigned u2 = *(const unsigned*)(fsh + o2);
                unsigned u3 = *(const unsigned*)(fsh + o3);
                unsigned u4 = *(const unsigned*)(fsh + o4);
                unsigned u5 = *(const unsigned*)(fsh + o5);
                unsigned u6 = *(const unsigned*)(fsh + o6);
                unsigned u7 = *(const unsigned*)(fsh + o7);
                pair_acc(u0, fd01, fd23, a01, a23, acc01, acc23, den, true);
                pair_acc(u1, fd01, fd23, a01, a23, acc01, acc23, den, true);
                pair_acc(u2, fd01, fd23, a01, a23, acc01, acc23, den, true);
                pair_acc(u3, fd01, fd23, a01, a23, acc01, acc23, den, true);
                pair_acc(u4, fd01, fd23, a01, a23, acc01, acc23, den, true);
                pair_acc(u5, fd01, fd23, a01, a23, acc01, acc23, den, true);
                pair_acc(u6, fd01, fd23, a01, a23, acc01, acc23, den, true);
                pair_acc(u7, fd01, fd23, a01, a23, acc01, acc23, den, true);
            }
            for (; j + 8 <= m; j += 8) {  // 4 pair-slots = 8 edges
                unsigned o0 = ((unsigned)__shfl(myadj, j + 0 + e2, 64) << 7) + suboff;
                unsigned o1 = ((unsigned)__shfl(myadj, j + 2 + e2, 64) << 7) + suboff;
                unsigned o2 = ((unsigned)__shfl(myadj, j + 4 + e2, 64) << 7) + suboff;
                unsigned o3 = ((unsigned)__shfl(myadj, j + 6 + e2, 64) << 7) + suboff;
                unsigned u0 = *(const unsigned*)(fsh + o0);
                unsigned u1 = *(const unsigned*)(fsh + o1);
                unsigned u2 = *(const unsigned*)(fsh + o2);
                unsigned u3 = *(const unsigned*)(fsh + o3);
                pair_acc(u0, fd01, fd23, a01, a23, acc01, acc23, den, true);
                pair_acc(u1, fd01, fd23, a01, a23, acc01, acc23, den, true);
                pair_acc(u2, fd01, fd23, a01, a23, acc01, acc23, den, true);
                pair_acc(u3, fd01, fd23, a01, a23, acc01, acc23, den, true);
            }
            for (; j < m; j += 2) {  // tail pairs (possibly half-valid)
                int idx = j + e2;
                bool valid = idx < m;
                unsigned o = ((unsigned)__shfl(myadj, valid ? idx : j, 64) << 7) + suboff;
                unsigned u = *(const unsigned*)(fsh + o);
                pair_acc(u, fd01, fd23, a01, a23, acc01, acc23, den, valid);
            }
        }
        // combine edge-parity halves
        den += __shfl_xor(den, 32, 64);
        float ax = acc01.x, ay = acc01.y, az = acc23.x, aw = acc23.y;
        ax += __shfl_xor(ax, 32, 64);
        ay += __shfl_xor(ay, 32, 64);
        az += __shfl_xor(az, 32, 64);
        aw += __shfl_xor(aw, 32, 64);
        float inv = den > 0.f ? (0.25f / FSCALE) / den : 0.f;  // head-mean + unscale
        float4 o;
        o.x = ax * inv;
        o.y = ay * inv;
        o.z = az * inv;
        o.w = aw * inv;
        // head mean: sum over sub^8, sub^16
        o.x += __shfl_xor(o.x, 8, 64);
        o.y += __shfl_xor(o.y, 8, 64);
        o.z += __shfl_xor(o.z, 8, 64);
        o.w += __shfl_xor(o.w, 8, 64);
        o.x += __shfl_xor(o.x, 16, 64);
        o.y += __shfl_xor(o.y, 16, 64);
        o.z += __shfl_xor(o.z, 16, 64);
        o.w += __shfl_xor(o.w, 16, 64);
        if (mode == 0) {
            if (lane < 8) {
                o.x = fmaxf(o.x, 0.f);
                o.y = fmaxf(o.y, 0.f);
                o.z = fmaxf(o.z, 0.f);
                o.w = fmaxf(o.w, 0.f);
                ((float4*)(xout + (size_t)n * 32))[lane] = o;
            }
        } else {
            racc.x += o.x;
            racc.y += o.y;
            racc.z += o.z;
            racc.w += o.w;
        }
        // rotate pipeline
        fdu = fdu_n;
        adjc = adjc_n;
        beg = beg_n;
        end = end_n;
    }
    if (mode == 1 && lane < 8) {
        float* gp = gpart + (wg & (NGRP - 1)) * 32 + lane * 4;
        atomicAdd(&gp[0], racc.x);
        atomicAdd(&gp[1], racc.y);
        atomicAdd(&gp[2], racc.z);
        atomicAdd(&gp[3], racc.w);
    }
}

__global__ void k_final(const float* __restrict__ gpart, const float* __restrict__ Wh1,
                        const float* __restrict__ bh1, const float* __restrict__ Wh2,
                        const float* __restrict__ bh2, float* __restrict__ out) {
    __shared__ float gv[32], gh[32], lg[16];
    int t = threadIdx.x;
    if (t < 32) {
        float s = 0.f;
        for (int b = 0; b < NGRP; b++) s += gpart[b * 32 + t];
        gv[t] = s * (1.f / (float)N_NODES);
    }
    __syncthreads();
    if (t < 32) {
        float s = bh1[t];
        for (int d = 0; d < 32; d++) s += gv[d] * Wh1[d * 32 + t];
        gh[t] = s > 0.f ? s : 0.f;
    }
    __syncthreads();
    if (t < NCLS) {
        float s = bh2[t];
        for (int j = 0; j < 32; j++) s += gh[j] * Wh2[j * NCLS + t];
        lg[t] = s;
    }
    __syncthreads();
    if (t == 0) {
        float m = lg[0];
        for (int c = 1; c < NCLS; c++) m = fmaxf(m, lg[c]);
        float ex[NCLS], sum = 0.f;
        for (int c = 0; c < NCLS; c++) {
            ex[c] = __expf(lg[c] - m);
            sum += ex[c];
        }
        float inv = 1.f / sum;
        for (int c = 0; c < NCLS; c++) out[c] = ex[c] * inv;
    }
}

extern "C" void kernel_launch(void* const* d_in, const int* in_sizes, int n_in,
                              void* d_out, int out_size, void* d_ws, size_t ws_size,
                              hipStream_t stream) {
    const float* g_feats = (const float*)d_in[0];
    const int* edge_src = (const int*)d_in[1];
    const int* edge_dst = (const int*)d_in[2];
    const float* W_in = (const float*)d_in[3];
    const float* b_in = (const float*)d_in[4];
    const float* W1_src = (const float*)d_in[5];
    const float* b1_src = (const float*)d_in[6];
    const float* W1_dst = (const float*)d_in[7];
    const float* b1_dst = (const float*)d_in[8];
    const float* attn1 = (const float*)d_in[9];
    const float* W2_src = (const float*)d_in[10];
    const float* b2_src = (const float*)d_in[11];
    const float* W2_dst = (const float*)d_in[12];
    const float* b2_dst = (const float*)d_in[13];
    const float* attn2 = (const float*)d_in[14];
    const float* Wh1 = (const float*)d_in[15];
    const float* bh1 = (const float*)d_in[16];
    const float* Wh2 = (const float*)d_in[17];
    const float* bh2 = (const float*)d_in[18];

    // workspace layout
    float* x = (float*)d_ws;                                          // N*32 f32
    unsigned char* fsh = (unsigned char*)(x + (size_t)N_NODES * 32);  // N*128 fp8
    unsigned short* fdh = (unsigned short*)(fsh + (size_t)N_NODES * 128);  // N*128 bf16
    float* gpart = (float*)(fdh + (size_t)N_NODES * 128);             // NGRP*32
    int* bhist = (int*)(gpart + NGRP * 32);                           // NBUCK
    int* bbase = bhist + NBUCK;                                       // NBUCK+1
    int* gcur = bbase + NBUCK + 1;                                    // NBUCK
    int* row = gcur + NBUCK;                                          // N+1
    unsigned* stage = (unsigned*)(row + N_NODES + 1);                 // E
    unsigned short* adj = (unsigned short*)(stage + N_EDGES);         // E u16

    const int PB = (N_NODES / NPW + 3) / 4;      // 500 proj blocks
    const int GB = (N_NODES / NPG + 3) / 4;      // 1563 gather blocks

    // zero gpart + bucket histogram in one memset (adjacent)
    hipMemsetAsync(gpart, 0, (NGRP * 32 + NBUCK) * sizeof(int), stream);

    // layer-1 proj || bucket histogram (independent; co-scheduled)
    k_f1h<<<F1B + HB, 256, 0, stream>>>(g_feats, W_in, b_in, W1_src, b1_src, W1_dst,
                                        b1_dst, fsh, fdh, edge_dst, bhist);

    // CSR build (binned)
    k_bscan<<<1, 256, 0, stream>>>(bhist, bbase, gcur);
    k_bin<<<(N_EDGES + 4095) / 4096, 256, 0, stream>>>(edge_src, edge_dst, gcur, stage);
    k_csr<<<NBUCK, 256, 0, stream>>>(stage, bbase, row, adj);

    // layer 1 gather
    k_gather<<<GB, 256, 0, stream>>>(fsh, fdh, attn1, row, adj, x, gpart, 0);

    // layer 2 (gather fuses the graph-mean reduction)
    k_proj<<<PB, 256, 0, stream>>>(x, W2_src, b2_src, W2_dst, b2_dst, fsh, fdh);
    k_gather<<<GB, 256, 0, stream>>>(fsh, fdh, attn2, row, adj, x, gpart, 1);

    k_final<<<1, 256, 0, stream>>>(gpart, Wh1, bh1, Wh2, bh2, (float*)d_out);
}

// Round 16
// 184.336 us; speedup vs baseline: 1.0816x; 1.0221x over previous
//
#include <hip/hip_runtime.h>
#include <hip/hip_bf16.h>

#define N_NODES 50000
#define N_EDGES 800000
#define DIM_IN 64
#define DIM_H 32
#define HEADS 4
#define NCLS 10
#define NEG 0.2f
#define NBUCK 196  // ceil(50000/256) buckets of 256 dst nodes
#define NPW 25     // nodes per wave in proj kernels (50000 = 2000 waves * 25)
#define FSCALE 16.0f  // fs/fd stored 16x (leaky is pos-homogeneous; attn/16)
#define LOG2E 1.44269504088896f

typedef float floatx2 __attribute__((ext_vector_type(2)));

__device__ __forceinline__ float fast_exp2(float x) {
#if __has_builtin(__builtin_amdgcn_exp2f)
    return __builtin_amdgcn_exp2f(x);
#else
    return __expf(x * 0.69314718055994531f);
#endif
}

// ---------------- CSR build (binned, single-writer adj regions) ----------------

__global__ void k_bhist(const int* __restrict__ dst, int* __restrict__ bh) {
    __shared__ int lh[NBUCK];
    for (int i = threadIdx.x; i < NBUCK; i += 256) lh[i] = 0;
    __syncthreads();
    int base = blockIdx.x * 1024 + threadIdx.x;
#pragma unroll
    for (int r = 0; r < 4; r++) {
        int e = base + r * 256;
        if (e < N_EDGES) atomicAdd(&lh[dst[e] >> 8], 1);
    }
    __syncthreads();
    for (int i = threadIdx.x; i < NBUCK; i += 256) {
        int c = lh[i];
        if (c) atomicAdd(&bh[i], c);
    }
}

__global__ void k_bscan(const int* __restrict__ bh, int* __restrict__ bbase,
                        int* __restrict__ gcur) {
    __shared__ int s[256];
    int t = threadIdx.x;
    int v = (t < NBUCK) ? bh[t] : 0;
    s[t] = v;
    __syncthreads();
    for (int off = 1; off < 256; off <<= 1) {
        int u = (t >= off) ? s[t - off] : 0;
        __syncthreads();
        s[t] += u;
        __syncthreads();
    }
    int excl = s[t] - v;
    if (t < NBUCK) {
        bbase[t] = excl;
        gcur[t] = excl;
    }
    if (t == 0) bbase[NBUCK] = N_EDGES;
}

__global__ void k_bin(const int* __restrict__ src, const int* __restrict__ dst,
                      int* __restrict__ gcur, unsigned* __restrict__ stage) {
    __shared__ int lh[NBUCK], chunk[NBUCK];
    int t = threadIdx.x;
    for (int i = t; i < NBUCK; i += 256) lh[i] = 0;
    __syncthreads();
    int e0 = blockIdx.x * 4096;
    unsigned pk[16];
    int bk[16];
#pragma unroll
    for (int r = 0; r < 16; r++) {
        int e = e0 + r * 256 + t;
        bool ok = e < N_EDGES;
        int s = ok ? src[e] : 0;
        int d = ok ? dst[e] : 0;
        bk[r] = ok ? (d >> 8) : -1;
        pk[r] = (unsigned)s | ((unsigned)(d & 255) << 16);
        if (ok) atomicAdd(&lh[bk[r]], 1);
    }
    __syncthreads();
    for (int i = t; i < NBUCK; i += 256) {
        int c = lh[i];
        chunk[i] = c ? atomicAdd(&gcur[i], c) : 0;
        lh[i] = 0;  // reuse as local cursor
    }
    __syncthreads();
#pragma unroll
    for (int r = 0; r < 16; r++) {
        if (bk[r] >= 0) {
            int lp = atomicAdd(&lh[bk[r]], 1);
            stage[chunk[bk[r]] + lp] = pk[r];
        }
    }
}

__global__ void k_csr(const unsigned* __restrict__ stage, const int* __restrict__ bbase,
                      int* __restrict__ row, unsigned short* __restrict__ adj) {
    __shared__ int lcnt[256], lcur[256], sc[256];
    int b = blockIdx.x, t = threadIdx.x;
    int s0 = bbase[b], s1 = bbase[b + 1];
    lcnt[t] = 0;
    __syncthreads();
    for (int i = s0 + t; i < s1; i += 256) atomicAdd(&lcnt[stage[i] >> 16], 1);
    __syncthreads();
    int v = lcnt[t];
    sc[t] = v;
    __syncthreads();
    for (int off = 1; off < 256; off <<= 1) {
        int u = (t >= off) ? sc[t - off] : 0;
        __syncthreads();
        sc[t] += u;
        __syncthreads();
    }
    int excl = sc[t] - v;
    int n = b * 256 + t;
    if (n < N_NODES) row[n] = s0 + excl;
    if (b == NBUCK - 1 && t == 0) row[N_NODES] = N_EDGES;
    lcur[t] = s0 + excl;
    __syncthreads();
    for (int i = s0 + t; i < s1; i += 256) {
        unsigned p = stage[i];
        int pos = atomicAdd(&lcur[p >> 16], 1);
        adj[pos] = (unsigned short)(p & 0xFFFFu);  // src fits 16 bits
    }
}

// ---------------- helpers ----------------

__device__ __forceinline__ unsigned short f2bf(float v) {  // RTN f32->bf16
    unsigned u = __builtin_bit_cast(unsigned, v);
    u += 0x7FFFu + ((u >> 16) & 1u);
    return (unsigned short)(u >> 16);
}
__device__ __forceinline__ float bf2f(unsigned short h) {
    return __builtin_bit_cast(float, (unsigned)h << 16);
}

// ---------------- layer-1: fused embed + projection ----------------
// Per node (low-rank, 10240 MACs): x = gf_row@W_in+b_in (64->32), then
// fs|fd = x@[W1s|W1d]+[b1s|b1d] (32->256), stored 16x-scaled; fs fp8, fd bf16.
__global__ __launch_bounds__(256, 2) void k_fused1(
    const float* __restrict__ gf, const float* __restrict__ W_in,
    const float* __restrict__ b_in, const float* __restrict__ W1s,
    const float* __restrict__ b1s, const float* __restrict__ W1d,
    const float* __restrict__ b1d, unsigned char* __restrict__ fsh,
    unsigned short* __restrict__ fdh) {
    __shared__ float4 xb[4][2][8];  // [wave][dbuf][32 floats]
    int lane = threadIdx.x & 63;
    int wvl = threadIdx.x >> 6;
    int wave = (blockIdx.x * 256 + threadIdx.x) >> 6;
    int c = lane & 31, h = lane >> 5;
    int n0 = wave * NPW;
    if (n0 >= N_NODES) return;
    float wi[32];
#pragma unroll
    for (int k = 0; k < 32; k++) wi[k] = W_in[(h * 32 + k) * DIM_H + c];
    float bc = b_in[c];
    const float4* Wb = (lane < 32) ? (const float4*)W1s : (const float4*)W1d;
    const float4* bb = (lane < 32) ? (const float4*)b1s : (const float4*)b1d;
    float4 w[32];
#pragma unroll
    for (int k = 0; k < 32; k++) w[k] = Wb[k * 32 + c];
    float4 bias = bb[c];
#pragma unroll 2
    for (int i = 0; i < NPW; i++) {  // 50000 % 25 == 0: all nodes valid
        int nu = __builtin_amdgcn_readfirstlane(n0 + i);
        const float4* gr = (const float4*)(gf + (size_t)nu * DIM_IN + h * 32);
        float a1 = 0.f;
#pragma unroll
        for (int k4 = 0; k4 < 8; k4++) {
            float4 xv = gr[k4];
            a1 += xv.x * wi[k4 * 4 + 0];
            a1 += xv.y * wi[k4 * 4 + 1];
            a1 += xv.z * wi[k4 * 4 + 2];
            a1 += xv.w * wi[k4 * 4 + 3];
        }
        a1 += __shfl_xor(a1, 32, 64);
        if (lane < 32) ((float*)&xb[wvl][i & 1][0])[c] = a1 + bc;
        float4 acc = bias;
#pragma unroll
        for (int k4 = 0; k4 < 8; k4++) {
            float4 xv = xb[wvl][i & 1][k4];
#pragma unroll
            for (int j = 0; j < 4; j++) {
                float xk = (j == 0) ? xv.x : (j == 1) ? xv.y : (j == 2) ? xv.z : xv.w;
                float4 wk = w[k4 * 4 + j];
                acc.x += xk * wk.x;
                acc.y += xk * wk.y;
                acc.z += xk * wk.z;
                acc.w += xk * wk.w;
            }
        }
        if (lane < 32) {
            int pk = __builtin_amdgcn_cvt_pk_fp8_f32(acc.x * FSCALE, acc.y * FSCALE,
                                                     0, false);
            pk = __builtin_amdgcn_cvt_pk_fp8_f32(acc.z * FSCALE, acc.w * FSCALE,
                                                 pk, true);
            *(int*)&fsh[(size_t)nu * 128 + c * 4] = pk;
        } else {
            ushort4 o;
            o.x = f2bf(acc.x * FSCALE);
            o.y = f2bf(acc.y * FSCALE);
            o.z = f2bf(acc.z * FSCALE);
            o.w = f2bf(acc.w * FSCALE);
            *(ushort4*)&fdh[(size_t)nu * 128 + c * 4] = o;
        }
    }
}

// ---------------- layer-2 projection (weights-in-registers) ----------------
__global__ __launch_bounds__(256, 2) void k_proj(
    const float* __restrict__ x, const float* __restrict__ Wsrc,
    const float* __restrict__ bsrc, const float* __restrict__ Wdst,
    const float* __restrict__ bdst, unsigned char* __restrict__ fsh,
    unsigned short* __restrict__ fdh) {
    int lane = threadIdx.x & 63;
    int wave = (blockIdx.x * 256 + threadIdx.x) >> 6;
    int cl = lane & 31;
    int n0 = wave * NPW;
    if (n0 >= N_NODES) return;
    const float4* Wb = (lane < 32) ? (const float4*)Wsrc : (const float4*)Wdst;
    const float4* bb = (lane < 32) ? (const float4*)bsrc : (const float4*)bdst;
    float4 w[32];
#pragma unroll
    for (int k = 0; k < 32; k++) w[k] = Wb[k * 32 + cl];
    float4 bias = bb[cl];
#pragma unroll 2
    for (int i = 0; i < NPW; i++) {
        int nu = __builtin_amdgcn_readfirstlane(n0 + i);
        const float4* xr = (const float4*)(x + (size_t)nu * DIM_H);
        float4 acc = bias;
#pragma unroll
        for (int k4 = 0; k4 < 8; k4++) {
            float4 xv = xr[k4];
#pragma unroll
            for (int j = 0; j < 4; j++) {
                float xk = (j == 0) ? xv.x : (j == 1) ? xv.y : (j == 2) ? xv.z : xv.w;
                float4 wk = w[k4 * 4 + j];
                acc.x += xk * wk.x;
                acc.y += xk * wk.y;
                acc.z += xk * wk.z;
                acc.w += xk * wk.w;
            }
        }
        if (lane < 32) {
            int pk = __builtin_amdgcn_cvt_pk_fp8_f32(acc.x * FSCALE, acc.y * FSCALE,
                                                     0, false);
            pk = __builtin_amdgcn_cvt_pk_fp8_f32(acc.z * FSCALE, acc.w * FSCALE,
                                                 pk, true);
            *(int*)&fsh[(size_t)nu * 128 + cl * 4] = pk;
        } else {
            ushort4 o;
            o.x = f2bf(acc.x * FSCALE);
            o.y = f2bf(acc.y * FSCALE);
            o.z = f2bf(acc.z * FSCALE);
            o.w = f2bf(acc.w * FSCALE);
            *(ushort4*)&fdh[(size_t)nu * 128 + cl * 4] = o;
        }
    }
}

// ---------------- GAT gather (fp8 rows, packed-f32 math) ----------------
// One wave per destination node. Lane = (e2=lane>>5, sub=lane&31). Lane owns
// dims sub*4..+3 of its edge's 128B fp8 row: one dword load, unpacked by
// v_cvt_pk_f32_fp8. floatx2 ops -> v_pk_{add,mul,fma}_f32. Head h=sub>>3:
// score reduce = 3 shfl_xor over 8 lanes. attn prescaled by log2e/16 so
// w = v_exp (base-2) directly. fs/fd 16x-scaled; 0.25/16 folded into inv.
__device__ __forceinline__ void pair_acc(unsigned u, floatx2 fd01, floatx2 fd23,
                                         floatx2 a01, floatx2 a23, floatx2& acc01,
                                         floatx2& acc23, float& den, bool valid) {
    floatx2 f01 = __builtin_amdgcn_cvt_pk_f32_fp8((int)u, false);
    floatx2 f23 = __builtin_amdgcn_cvt_pk_f32_fp8((int)u, true);
    floatx2 t01 = f01 + fd01;
    floatx2 t23 = f23 + fd23;
    floatx2 n01 = t01 * NEG;
    floatx2 n23 = t23 * NEG;
    floatx2 l01, l23;
    l01.x = fmaxf(t01.x, n01.x);
    l01.y = fmaxf(t01.y, n01.y);
    l23.x = fmaxf(t23.x, n23.x);
    l23.y = fmaxf(t23.y, n23.y);
    floatx2 d = l01 * a01 + l23 * a23;  // pk_mul + pk_fma
    float p = d.x + d.y;
    p += __shfl_xor(p, 1, 64);
    p += __shfl_xor(p, 2, 64);
    p += __shfl_xor(p, 4, 64);
    float w = fast_exp2(p);
    if (!valid) w = 0.f;
    den += w;
    floatx2 wv = {w, w};
    acc01 += wv * f01;
    acc23 += wv * f23;
}

__global__ void k_gather(const unsigned char* __restrict__ fsh,
                         const unsigned short* __restrict__ fdh,
                         const float* __restrict__ attn, const int* __restrict__ row,
                         const unsigned short* __restrict__ adj,
                         float* __restrict__ xout, float* __restrict__ gpart,
                         int mode) {  // mode 0: relu + store x; 1: graph-mean reduce
    __shared__ float bsum[32];
    int tid = threadIdx.x;
    if (mode) {
        if (tid < 32) bsum[tid] = 0.f;
        __syncthreads();
    }
    int wave = tid >> 6;
    int lane = tid & 63;
    int n = blockIdx.x * 4 + wave;  // 50000 = 12500 * 4: always valid
    int sub = lane & 31, e2 = lane >> 5;
    unsigned suboff = (unsigned)sub << 2;  // 4B per lane within 128B row
    float4 a4 = ((const float4*)attn)[sub];
    const float asc = LOG2E / FSCALE;
    floatx2 a01 = {a4.x * asc, a4.y * asc};
    floatx2 a23 = {a4.z * asc, a4.w * asc};
    ushort4 fdu = *(const ushort4*)(fdh + (size_t)n * 128 + sub * 4);
    floatx2 fd01 = {bf2f(fdu.x), bf2f(fdu.y)};
    floatx2 fd23 = {bf2f(fdu.z), bf2f(fdu.w)};
    floatx2 acc01 = {0.f, 0.f}, acc23 = {0.f, 0.f};
    float den = 0.f;
    int beg = row[n], end = row[n + 1];
    for (int base = beg; base < end; base += 64) {
        int m = end - base;
        if (m > 64) m = 64;
        int myadj = (lane < m) ? (int)adj[base + lane] : 0;
        int j = 0;
        for (; j + 16 <= m; j += 16) {  // 8 pair-slots = 16 edges, 8 loads in flight
            unsigned o0 = ((unsigned)__shfl(myadj, j + 0 + e2, 64) << 7) + suboff;
            unsigned o1 = ((unsigned)__shfl(myadj, j + 2 + e2, 64) << 7) + suboff;
            unsigned o2 = ((unsigned)__shfl(myadj, j + 4 + e2, 64) << 7) + suboff;
            unsigned o3 = ((unsigned)__shfl(myadj, j + 6 + e2, 64) << 7) + suboff;
            unsigned o4 = ((unsigned)__shfl(myadj, j + 8 + e2, 64) << 7) + suboff;
            unsigned o5 = ((unsigned)__shfl(myadj, j + 10 + e2, 64) << 7) + suboff;
            unsigned o6 = ((unsigned)__shfl(myadj, j + 12 + e2, 64) << 7) + suboff;
            unsigned o7 = ((unsigned)__shfl(myadj, j + 14 + e2, 64) << 7) + suboff;
            unsigned u0 = *(const unsigned*)(fsh + o0);
            unsigned u1 = *(const unsigned*)(fsh + o1);
            unsigned u2 = *(const unsigned*)(fsh + o2);
            unsigned u3 = *(const unsigned*)(fsh + o3);
            unsigned u4 = *(const unsigned*)(fsh + o4);
            unsigned u5 = *(const unsigned*)(fsh + o5);
            unsigned u6 = *(const unsigned*)(fsh + o6);
            unsigned u7 = *(const unsigned*)(fsh + o7);
            pair_acc(u0, fd01, fd23, a01, a23, acc01, acc23, den, true);
            pair_acc(u1, fd01, fd23, a01, a23, acc01, acc23, den, true);
            pair_acc(u2, fd01, fd23, a01, a23, acc01, acc23, den, true);
            pair_acc(u3, fd01, fd23, a01, a23, acc01, acc23, den, true);
            pair_acc(u4, fd01, fd23, a01, a23, acc01, acc23, den, true);
            pair_acc(u5, fd01, fd23, a01, a23, acc01, acc23, den, true);
            pair_acc(u6, fd01, fd23, a01, a23, acc01, acc23, den, true);
            pair_acc(u7, fd01, fd23, a01, a23, acc01, acc23, den, true);
        }
        for (; j + 8 <= m; j += 8) {  // 4 pair-slots = 8 edges
            unsigned o0 = ((unsigned)__shfl(myadj, j + 0 + e2, 64) << 7) + suboff;
            unsigned o1 = ((unsigned)__shfl(myadj, j + 2 + e2, 64) << 7) + suboff;
            unsigned o2 = ((unsigned)__shfl(myadj, j + 4 + e2, 64) << 7) + suboff;
            unsigned o3 = ((unsigned)__shfl(myadj, j + 6 + e2, 64) << 7) + suboff;
            unsigned u0 = *(const unsigned*)(fsh + o0);
            unsigned u1 = *(const unsigned*)(fsh + o1);
            unsigned u2 = *(const unsigned*)(fsh + o2);
            unsigned u3 = *(const unsigned*)(fsh + o3);
            pair_acc(u0, fd01, fd23, a01, a23, acc01, acc23, den, true);
            pair_acc(u1, fd01, fd23, a01, a23, acc01, acc23, den, true);
            pair_acc(u2, fd01, fd23, a01, a23, acc01, acc23, den, true);
            pair_acc(u3, fd01, fd23, a01, a23, acc01, acc23, den, true);
        }
        for (; j < m; j += 2) {  // tail pairs (possibly half-valid)
            int idx = j + e2;
            bool valid = idx < m;
            unsigned o = ((unsigned)__shfl(myadj, valid ? idx : j, 64) << 7) + suboff;
            unsigned u = *(const unsigned*)(fsh + o);
            pair_acc(u, fd01, fd23, a01, a23, acc01, acc23, den, valid);
        }
    }
    // combine edge-parity halves
    den += __shfl_xor(den, 32, 64);
    float ax = acc01.x, ay = acc01.y, az = acc23.x, aw = acc23.y;
    ax += __shfl_xor(ax, 32, 64);
    ay += __shfl_xor(ay, 32, 64);
    az += __shfl_xor(az, 32, 64);
    aw += __shfl_xor(aw, 32, 64);
    float inv = den > 0.f ? (0.25f / FSCALE) / den : 0.f;  // head-mean + unscale
    float4 o;
    o.x = ax * inv;
    o.y = ay * inv;
    o.z = az * inv;
    o.w = aw * inv;
    // head mean: sum over sub^8, sub^16
    o.x += __shfl_xor(o.x, 8, 64);
    o.y += __shfl_xor(o.y, 8, 64);
    o.z += __shfl_xor(o.z, 8, 64);
    o.w += __shfl_xor(o.w, 8, 64);
    o.x += __shfl_xor(o.x, 16, 64);
    o.y += __shfl_xor(o.y, 16, 64);
    o.z += __shfl_xor(o.z, 16, 64);
    o.w += __shfl_xor(o.w, 16, 64);
    if (mode == 0) {
        if (lane < 8) {
            o.x = fmaxf(o.x, 0.f);
            o.y = fmaxf(o.y, 0.f);
            o.z = fmaxf(o.z, 0.f);
            o.w = fmaxf(o.w, 0.f);
            ((float4*)(xout + (size_t)n * 32))[lane] = o;
        }
    } else {
        if (lane < 8) {
            atomicAdd(&bsum[lane * 4 + 0], o.x);
            atomicAdd(&bsum[lane * 4 + 1], o.y);
            atomicAdd(&bsum[lane * 4 + 2], o.z);
            atomicAdd(&bsum[lane * 4 + 3], o.w);
        }
        __syncthreads();
        if (tid < 32) atomicAdd(&gpart[(blockIdx.x & 63) * 32 + tid], bsum[tid]);
    }
}

__global__ void k_final(const float* __restrict__ gpart, const float* __restrict__ Wh1,
                        const float* __restrict__ bh1, const float* __restrict__ Wh2,
                        const float* __restrict__ bh2, float* __restrict__ out) {
    __shared__ float gv[32], gh[32], lg[16];
    int t = threadIdx.x;
    if (t < 32) {
        float s = 0.f;
        for (int b = 0; b < 64; b++) s += gpart[b * 32 + t];
        gv[t] = s * (1.f / (float)N_NODES);
    }
    __syncthreads();
    if (t < 32) {
        float s = bh1[t];
        for (int d = 0; d < 32; d++) s += gv[d] * Wh1[d * 32 + t];
        gh[t] = s > 0.f ? s : 0.f;
    }
    __syncthreads();
    if (t < NCLS) {
        float s = bh2[t];
        for (int j = 0; j < 32; j++) s += gh[j] * Wh2[j * NCLS + t];
        lg[t] = s;
    }
    __syncthreads();
    if (t == 0) {
        float m = lg[0];
        for (int c = 1; c < NCLS; c++) m = fmaxf(m, lg[c]);
        float ex[NCLS], sum = 0.f;
        for (int c = 0; c < NCLS; c++) {
            ex[c] = __expf(lg[c] - m);
            sum += ex[c];
        }
        float inv = 1.f / sum;
        for (int c = 0; c < NCLS; c++) out[c] = ex[c] * inv;
    }
}

extern "C" void kernel_launch(void* const* d_in, const int* in_sizes, int n_in,
                              void* d_out, int out_size, void* d_ws, size_t ws_size,
                              hipStream_t stream) {
    const float* g_feats = (const float*)d_in[0];
    const int* edge_src = (const int*)d_in[1];
    const int* edge_dst = (const int*)d_in[2];
    const float* W_in = (const float*)d_in[3];
    const float* b_in = (const float*)d_in[4];
    const float* W1_src = (const float*)d_in[5];
    const float* b1_src = (const float*)d_in[6];
    const float* W1_dst = (const float*)d_in[7];
    const float* b1_dst = (const float*)d_in[8];
    const float* attn1 = (const float*)d_in[9];
    const float* W2_src = (const float*)d_in[10];
    const float* b2_src = (const float*)d_in[11];
    const float* W2_dst = (const float*)d_in[12];
    const float* b2_dst = (const float*)d_in[13];
    const float* attn2 = (const float*)d_in[14];
    const float* Wh1 = (const float*)d_in[15];
    const float* bh1 = (const float*)d_in[16];
    const float* Wh2 = (const float*)d_in[17];
    const float* bh2 = (const float*)d_in[18];

    // workspace layout
    float* x = (float*)d_ws;                                          // N*32 f32
    unsigned char* fsh = (unsigned char*)(x + (size_t)N_NODES * 32);  // N*128 fp8
    unsigned short* fdh = (unsigned short*)(fsh + (size_t)N_NODES * 128);  // N*128 bf16
    float* gpart = (float*)(fdh + (size_t)N_NODES * 128);             // 64*32
    int* bh = (int*)(gpart + 64 * 32);                                // NBUCK
    int* bbase = bh + NBUCK;                                          // NBUCK+1
    int* gcur = bbase + NBUCK + 1;                                    // NBUCK
    int* row = gcur + NBUCK;                                          // N+1
    unsigned* stage = (unsigned*)(row + N_NODES + 1);                 // E
    unsigned short* adj = (unsigned short*)(stage + N_EDGES);         // E u16

    const int WB = (N_NODES / NPW + 3) / 4;  // 500 blocks: 4 waves x 25 nodes

    // zero gpart + bucket histogram in one memset (adjacent)
    hipMemsetAsync(gpart, 0, (64 * 32 + NBUCK) * sizeof(int), stream);

    // CSR build (binned)
    k_bhist<<<(N_EDGES + 1023) / 1024, 256, 0, stream>>>(edge_dst, bh);
    k_bscan<<<1, 256, 0, stream>>>(bh, bbase, gcur);
    k_bin<<<(N_EDGES + 4095) / 4096, 256, 0, stream>>>(edge_src, edge_dst, gcur, stage);
    k_csr<<<NBUCK, 256, 0, stream>>>(stage, bbase, row, adj);

    // layer 1 (pipeline-fused embed+proj, low-rank path)
    k_fused1<<<WB, 256, 0, stream>>>(g_feats, W_in, b_in, W1_src, b1_src, W1_dst,
                                     b1_dst, fsh, fdh);
    k_gather<<<N_NODES / 4, 256, 0, stream>>>(fsh, fdh, attn1, row, adj, x, gpart, 0);

    // layer 2 (gather fuses the graph-mean reduction)
    k_proj<<<WB, 256, 0, stream>>>(x, W2_src, b2_src, W2_dst, b2_dst, fsh, fdh);
    k_gather<<<N_NODES / 4, 256, 0, stream>>>(fsh, fdh, attn2, row, adj, x, gpart, 1);

    k_final<<<1, 256, 0, stream>>>(gpart, Wh1, bh1, Wh2, bh2, (float*)d_out);
}